// Round 7
// baseline (635.096 us; speedup 1.0000x reference)
//
#include <hip/hip_runtime.h>
#include <hip/hip_bf16.h>

// Problem constants
#define BB      16
#define CIN     768
#define HID     256
#define NCO     512       // both heads' conv1 outputs concatenated
#define NWI     37
#define NPOS    1369      // 37*37
#define PADW    39
#define PPAD    1521      // 39*39
#define PP      14
#define KOUT    1764      // 9*14*14
#define KOUTP   1792      // padded to 7*256
#define HOUT    518
#define CONF_OFF ((size_t)BB*2*HOUT*HOUT)
#define WROWS   1408      // padded positions per batch (11*128 = 22*64)

// Workspace layout (byte offsets)
//  h1f  : BB*HID*PPAD fp32 (padded; borders 0 — halo-read by conv3_small)
//  fpad : BB*3*PPAD  fp32 (padded; borders 0)
//  h1wb : BB*NPOS*HID bf16
//  tokb : BB*NPOS*CIN bf16   <- dead after conv1; REUSED as wraw (per-half)
//  wtb  : 9*NCO*CIN  bf16    <- dead after conv1; REUSED as wraw (per-half)
//  wt2b : KOUTP*HID  bf16
//  zero : 2 KiB zero page
static constexpr size_t B_H1F  = 0;
static constexpr size_t B_FPAD = B_H1F  + (size_t)BB*HID*PPAD*4;
static constexpr size_t B_H1WB = B_FPAD + (size_t)BB*3*PPAD*4;
static constexpr size_t B_TOK  = B_H1WB + (size_t)BB*NPOS*HID*2;
static constexpr size_t B_WTB  = B_TOK  + (size_t)BB*NPOS*CIN*2;
static constexpr size_t B_WT2B = B_WTB  + (size_t)9*NCO*CIN*2;
static constexpr size_t B_ZERO = B_WT2B + (size_t)KOUTP*HID*2;
// wraw half-buffer (8*1408*1792*2 = 40,370,176 B) aliases [B_TOK, B_WT2B)
// (40,722,432 B available — fits). Sequential stream ordering makes this safe.
static constexpr size_t B_WRAW = B_TOK;

typedef __attribute__((ext_vector_type(8))) __bf16 bf16x8;
typedef __attribute__((ext_vector_type(4))) float  f32x4;

__device__ __forceinline__ void gl_lds16(const void* g, void* l) {
    __builtin_amdgcn_global_load_lds(
        (const __attribute__((address_space(1))) unsigned int*)g,
        (__attribute__((address_space(3))) unsigned int*)l, 16, 0, 0);
}

// tokens fp32 -> bf16 (same [b][pos][ci] layout)
__global__ void cast_tok(const float* __restrict__ t, __hip_bfloat16* __restrict__ o, int n4) {
    for (int i = blockIdx.x * 256 + threadIdx.x; i < n4; i += gridDim.x * 256) {
        float4 v = reinterpret_cast<const float4*>(t)[i];
        union { __hip_bfloat16 h[4]; short4 s; } u;
        u.h[0] = __float2bfloat16(v.x); u.h[1] = __float2bfloat16(v.y);
        u.h[2] = __float2bfloat16(v.z); u.h[3] = __float2bfloat16(v.w);
        reinterpret_cast<short4*>(o)[i] = u.s;
    }
}

// fh_w1/wp_w1 [co][ci][3][3] -> wtb[kk][co(512)][ci] bf16 (coalesced both sides)
__global__ void build_wtb(const float* __restrict__ fh, const float* __restrict__ wp,
                          __hip_bfloat16* __restrict__ wtb) {
    int t = blockIdx.x * 256 + threadIdx.x;
    if (t >= NCO * CIN) return;
    int co = t / CIN, ci = t % CIN;
    const float* src = (co < HID) ? fh + ((size_t)co * CIN + ci) * 9
                                  : wp + ((size_t)(co - HID) * CIN + ci) * 9;
    #pragma unroll
    for (int kk = 0; kk < 9; ++kk)
        wtb[(size_t)kk * NCO * CIN + t] = __float2bfloat16(src[kk]);
}

// wp_w2 [KOUT][HID][1][1] -> wt2b [KOUTP][HID] bf16 (pad rows zero)
__global__ void cast_wt2b(const float* __restrict__ w, __hip_bfloat16* __restrict__ o) {
    int idx = blockIdx.x * 256 + threadIdx.x;
    if (idx >= KOUTP * HID) return;
    int co = idx / HID;
    o[idx] = (co < KOUT) ? __float2bfloat16(w[idx]) : __hip_bfloat16(0.f);
}

// Implicit-GEMM 3x3 conv via MFMA. R7: BM=64 x BN=128 (grid 1408 = 5.5 blk/CU,
// LDS 24KB -> ~6 blk/CU co-resident) to hide barrier-drain latency.
// XOR LDS swizzle both sides (R6-verified, conflicts=0). XCD-chunked swizzle.
__global__ __launch_bounds__(256) void conv1_mfma(
        const __hip_bfloat16* __restrict__ tok,
        const __hip_bfloat16* __restrict__ wtb,
        const float* __restrict__ fh_b1, const float* __restrict__ wp_b1,
        const char* __restrict__ zpage,
        float* __restrict__ h1f, __hip_bfloat16* __restrict__ h1wb) {
    __shared__ __align__(16) __hip_bfloat16 As[64 * 64];    // [pos][k], XOR-swizzled
    __shared__ __align__(16) __hip_bfloat16 Bs[128 * 64];   // [co][k],  XOR-swizzled
    // 1408 blocks = 8 XCDs x 176; co fastest (4 co-tiles share one A pos-tile).
    const int hw      = blockIdx.x;
    const int logical = (hw & 7) * 176 + (hw >> 3);
    const int co0  = (logical & 3) * 128;
    const int pos0 = ((logical >> 2) % 22) * 64;
    const int bb   = (logical >> 2) / 22;
    const int tid  = threadIdx.x;
    const int wv   = tid >> 6, lane = tid & 63;
    const int wr   = wv >> 1,  wc   = wv & 1;   // wave tile: 32 pos x 64 co

    // staging: chunk = 8 rows x 64 k (1 KB). lane: row = c*8 + lane>>3,
    // 16B slot (lane&7); XOR swizzle: fetch k-group (lane&7)^(lane>>3).
    const int cig = (((lane & 7) ^ (lane >> 3)) * 8);   // k offset (elements)
    // A: 8 chunks (c = wv*2+i), B: 16 chunks (c = wv*4+i)
    int h_i[2], w_i[2]; bool inb[2];
    const char* bsrcb[4];
    char *alds[2], *blds[4];
    #pragma unroll
    for (int i = 0; i < 2; ++i) {
        int c   = wv * 2 + i;
        int row = c * 8 + (lane >> 3);
        int pos = pos0 + row;
        inb[i] = pos < NPOS;
        h_i[i] = pos / NWI;
        w_i[i] = pos % NWI;
        alds[i] = (char*)As + c * 1024;
    }
    #pragma unroll
    for (int i = 0; i < 4; ++i) {
        int c   = wv * 4 + i;
        int row = c * 8 + (lane >> 3);
        bsrcb[i] = (const char*)wtb + (((size_t)(co0 + row)) * CIN + cig) * 2;
        blds[i]  = (char*)Bs + c * 1024;
    }

    f32x4 acc[2][4] = {};

    const int sw = ((lane >> 4) ^ (lane & 7)) * 16;
    const char* apx = (const char*)As + ((wr * 32 + (lane & 15)) * 64) * 2 + sw;
    const char* bpx = (const char*)Bs + ((wc * 64 + (lane & 15)) * 64) * 2 + sw;

    for (int kk = 0; kk < 9; ++kk) {
        const int dh = kk / 3 - 1, dw = kk % 3 - 1;
        const size_t kkoff = (size_t)kk * NCO * CIN * 2;
        const char* asrc[2];
        #pragma unroll
        for (int i = 0; i < 2; ++i) {
            int hh = h_i[i] + dh, ww = w_i[i] + dw;
            bool v = inb[i] && (unsigned)hh < NWI && (unsigned)ww < NWI;
            asrc[i] = v ? (const char*)tok + (((size_t)bb * NPOS + hh * NWI + ww) * CIN + cig) * 2
                        : zpage;
        }
        for (int k0 = 0; k0 < CIN; k0 += 64) {
            const int kb = k0 * 2;
            #pragma unroll
            for (int i = 0; i < 2; ++i) gl_lds16(asrc[i] + kb, alds[i]);
            #pragma unroll
            for (int i = 0; i < 4; ++i) gl_lds16(bsrcb[i] + kkoff + kb, blds[i]);
            __syncthreads();
            #pragma unroll
            for (int s = 0; s < 2; ++s) {
                bf16x8 af[2], bf[4];
                #pragma unroll
                for (int mf = 0; mf < 2; ++mf)
                    af[mf] = *reinterpret_cast<const bf16x8*>(
                        (const void*)((uintptr_t)(apx + mf * 16 * 128) ^ (uintptr_t)(s * 64)));
                #pragma unroll
                for (int nf = 0; nf < 4; ++nf)
                    bf[nf] = *reinterpret_cast<const bf16x8*>(
                        (const void*)((uintptr_t)(bpx + nf * 16 * 128) ^ (uintptr_t)(s * 64)));
                #pragma unroll
                for (int mf = 0; mf < 2; ++mf)
                    #pragma unroll
                    for (int nf = 0; nf < 4; ++nf)
                        acc[mf][nf] = __builtin_amdgcn_mfma_f32_16x16x32_bf16(
                            af[mf], bf[nf], acc[mf][nf], 0, 0, 0);
            }
            __syncthreads();
        }
    }

    // epilogue: C/D mapping (m89): n = lane&15, m = (lane>>4)*4 + r
    const bool  isF   = (co0 < HID);
    const float* bias = isF ? fh_b1 : wp_b1;
    const int cobase  = isF ? co0 : co0 - HID;
    const int nl = lane & 15, mh = (lane >> 4) * 4;
    #pragma unroll
    for (int mf = 0; mf < 2; ++mf) {
        #pragma unroll
        for (int r = 0; r < 4; ++r) {
            int pos = pos0 + wr * 32 + mf * 16 + mh + r;
            if (pos >= NPOS) continue;
            int h = pos / NWI, w = pos % NWI;
            #pragma unroll
            for (int nf = 0; nf < 4; ++nf) {
                int c = cobase + wc * 64 + nf * 16 + nl;
                float v = fmaxf(acc[mf][nf][r] + bias[c], 0.f);
                if (isF)
                    h1f[(((size_t)bb * HID + c) * PADW + h + 1) * PADW + w + 1] = v;
                else
                    h1wb[((size_t)bb * NPOS + pos) * HID + c] = __float2bfloat16(v);
            }
        }
    }
}

// 3x3 conv 256->3 (+bias, xP) -> padded fpad. 32 pos x 8 ci-groups per block.
__global__ __launch_bounds__(256) void conv3_small(const float* __restrict__ h1f,
                                                   const float* __restrict__ w2,
                                                   const float* __restrict__ b2,
                                                   float* __restrict__ fpad) {
    __shared__ float red[8][3][32];
    int tid = threadIdx.x;
    int pl = tid & 31, cg = tid >> 5;
    int idx = blockIdx.x * 32 + pl;
    int bb = 0, pos = 0;
    if (idx < BB * NPOS) { bb = idx / NPOS; pos = idx % NPOS; }
    int h = pos / NWI, w = pos % NWI;
    float a0 = 0.f, a1 = 0.f, a2 = 0.f;
    const float* xb = h1f + ((size_t)bb * HID + cg * 32) * PPAD;
    const float* wb = w2 + cg * 32 * 9;
    for (int cl = 0; cl < 32; ++cl) {
        const float* xr = xb + (size_t)cl * PPAD + h * PADW + w;
        #pragma unroll
        for (int kk = 0; kk < 9; ++kk) {
            float x = xr[(kk / 3) * PADW + (kk % 3)];
            a0 += x * wb[cl * 9 + kk];
            a1 += x * wb[2304 + cl * 9 + kk];
            a2 += x * wb[4608 + cl * 9 + kk];
        }
    }
    red[cg][0][pl] = a0; red[cg][1][pl] = a1; red[cg][2][pl] = a2;
    __syncthreads();
    if (tid < 96) {
        int c = tid >> 5, p2 = tid & 31;
        float s = 0.f;
        #pragma unroll
        for (int q = 0; q < 8; ++q) s += red[q][c][p2];
        int idx2 = blockIdx.x * 32 + p2;
        if (idx2 < BB * NPOS) {
            int b2i = idx2 / NPOS, ps = idx2 % NPOS;
            int hh = ps / NWI, ww = ps % NWI;
            fpad[(((size_t)b2i * 3 + c) * PADW + hh + 1) * PADW + ww + 1] = 14.f * (s + b2[c]);
        }
    }
}

// wraw GEMM (per batch-half of 8): M=8*1408 rows, N=1792, K=256. 128x128 tiles,
// conv1-proven structure. Epilogue: +bias -> bf16 wraw[row][co].
__global__ __launch_bounds__(256) void wraw_gemm(
        const __hip_bfloat16* __restrict__ h1wb_h,   // offset to half's batch 0
        const __hip_bfloat16* __restrict__ wt2b,
        const float* __restrict__ b2,
        __hip_bfloat16* __restrict__ wraw) {
    __shared__ __align__(16) __hip_bfloat16 As[128 * 64];
    __shared__ __align__(16) __hip_bfloat16 Bs[128 * 64];
    // grid 1232 = 8 XCDs x 154; co fastest (14 co-tiles share one A pos-tile)
    const int hw      = blockIdx.x;
    const int logical = (hw & 7) * 154 + (hw >> 3);
    const int co0  = (logical % 14) * 128;
    const int row0 = (logical / 14) * 128;
    const int tid  = threadIdx.x;
    const int wv   = tid >> 6, lane = tid & 63;
    const int wr   = wv >> 1,  wc   = wv & 1;

    const int cig = (((lane & 7) ^ (lane >> 3)) * 8);
    const char* asrcb[4];
    const char* bsrcb[4];
    char *alds[4], *blds[4];
    #pragma unroll
    for (int i = 0; i < 4; ++i) {
        int c   = wv * 4 + i;
        int row = c * 8 + (lane >> 3);
        int rm  = row0 + row;
        int b_l = rm / WROWS;
        int pos = rm - b_l * WROWS;
        if (pos >= NPOS) pos = NPOS - 1;   // clamp (pad rows: garbage, ignored)
        asrcb[i] = (const char*)h1wb_h + (((size_t)b_l * NPOS + pos) * HID + cig) * 2;
        bsrcb[i] = (const char*)wt2b + (((size_t)(co0 + row)) * HID + cig) * 2;
        alds[i]  = (char*)As + c * 1024;
        blds[i]  = (char*)Bs + c * 1024;
    }

    f32x4 acc[4][4] = {};
    const int sw = ((lane >> 4) ^ (lane & 7)) * 16;
    const char* apx = (const char*)As + ((wr * 64 + (lane & 15)) * 64) * 2 + sw;
    const char* bpx = (const char*)Bs + ((wc * 64 + (lane & 15)) * 64) * 2 + sw;

    for (int k0 = 0; k0 < HID; k0 += 64) {
        const int kb = k0 * 2;
        #pragma unroll
        for (int i = 0; i < 4; ++i) gl_lds16(asrcb[i] + kb, alds[i]);
        #pragma unroll
        for (int i = 0; i < 4; ++i) gl_lds16(bsrcb[i] + kb, blds[i]);
        __syncthreads();
        #pragma unroll
        for (int s = 0; s < 2; ++s) {
            bf16x8 af[4], bf[4];
            #pragma unroll
            for (int mf = 0; mf < 4; ++mf)
                af[mf] = *reinterpret_cast<const bf16x8*>(
                    (const void*)((uintptr_t)(apx + mf * 16 * 128) ^ (uintptr_t)(s * 64)));
            #pragma unroll
            for (int nf = 0; nf < 4; ++nf)
                bf[nf] = *reinterpret_cast<const bf16x8*>(
                    (const void*)((uintptr_t)(bpx + nf * 16 * 128) ^ (uintptr_t)(s * 64)));
            #pragma unroll
            for (int mf = 0; mf < 4; ++mf)
                #pragma unroll
                for (int nf = 0; nf < 4; ++nf)
                    acc[mf][nf] = __builtin_amdgcn_mfma_f32_16x16x32_bf16(
                        af[mf], bf[nf], acc[mf][nf], 0, 0, 0);
        }
        __syncthreads();
    }

    const int nl = lane & 15, mh = (lane >> 4) * 4;
    #pragma unroll
    for (int mf = 0; mf < 4; ++mf) {
        #pragma unroll
        for (int r = 0; r < 4; ++r) {
            int rm = row0 + wr * 64 + mf * 16 + mh + r;
            #pragma unroll
            for (int nf = 0; nf < 4; ++nf) {
                int c = co0 + wc * 64 + nf * 16 + nl;
                float bz = (c < KOUT) ? b2[c] : 0.f;
                wraw[(size_t)rm * KOUTP + c] = __float2bfloat16(acc[mf][nf][r] + bz);
            }
        }
    }
}

// Tail (per half): softmax(9) + neighbor einsum + pixel shuffle + sigmoid.
// 8 positions per block; wraw rows staged to LDS coalesced.
__global__ __launch_bounds__(256) void up_tail(const __hip_bfloat16* __restrict__ wraw,
                                               const float* __restrict__ fpad,
                                               float* __restrict__ out, int half) {
    __shared__ __hip_bfloat16 rows8[8][KOUTP];   // 28 KB
    __shared__ float nbr[8][27];
    const int b_l = blockIdx.y, bb = half * 8 + b_l;
    const int pos0 = blockIdx.x * 8;
    const int tid = threadIdx.x;

    // stage 8 wraw rows (coalesced short8)
    const size_t rbase = ((size_t)b_l * WROWS + pos0) * KOUTP;
    #pragma unroll
    for (int e = 0; e < 7; ++e) {
        int t = tid + e * 256;                   // t in [0, 1792)
        int p = t >> 8, slot = t & 255;          // 256 slots x 8 rows? (8*224=1792)
        // KOUTP/8 = 224 slots per row -> index via div by 224
        p = t / 224; slot = t - p * 224;
        reinterpret_cast<short4*>(&rows8[p][slot * 8])[0] =
            reinterpret_cast<const short4*>(wraw + rbase + (size_t)p * KOUTP + slot * 8)[0];
        reinterpret_cast<short4*>(&rows8[p][slot * 8 + 4])[0] =
            reinterpret_cast<const short4*>(wraw + rbase + (size_t)p * KOUTP + slot * 8 + 4)[0];
    }
    // neighbor staging (padded fpad: borders zero)
    if (tid < 8 * 27) {
        int p = tid / 27, r = tid % 27;
        int c = r / 9, k = r % 9;
        int i = k / 3, j = k % 3;
        int pos = pos0 + p; float v = 0.f;
        if (pos < NPOS) {
            int h = pos / NWI, w = pos % NWI;
            v = fpad[(((size_t)bb * 3 + c) * PADW + h + i) * PADW + w + j];
        }
        nbr[p][r] = v;
    }
    __syncthreads();

    for (int t = tid; t < 8 * 196; t += 256) {
        int p = t / 196, pq = t % 196;
        int pos = pos0 + p; if (pos >= NPOS) continue;
        float v[9]; float m = -1e30f;
        #pragma unroll
        for (int k = 0; k < 9; ++k) {
            v[k] = __bfloat162float(rows8[p][k * 196 + pq]);
            m = fmaxf(m, v[k]);
        }
        float s = 0.f;
        #pragma unroll
        for (int k = 0; k < 9; ++k) { v[k] = __expf(v[k] - m); s += v[k]; }
        float inv = 1.f / s;
        int h = pos / NWI, w = pos % NWI;
        int pp = pq / PP, qq = pq % PP;
        int Y = h * PP + pp, X = w * PP + qq;
        const float* nb = &nbr[p][0];
        float u0 = 0.f, u1 = 0.f, u2 = 0.f;
        #pragma unroll
        for (int k = 0; k < 9; ++k) {
            u0 += v[k] * nb[k]; u1 += v[k] * nb[9 + k]; u2 += v[k] * nb[18 + k];
        }
        out[(((size_t)bb * 2 + 0) * HOUT + Y) * HOUT + X] = u0 * inv;
        out[(((size_t)bb * 2 + 1) * HOUT + Y) * HOUT + X] = u1 * inv;
        out[CONF_OFF + ((size_t)bb * HOUT + Y) * HOUT + X] = 1.f / (1.f + __expf(-u2 * inv));
    }
}

extern "C" void kernel_launch(void* const* d_in, const int* in_sizes, int n_in,
                              void* d_out, int out_size, void* d_ws, size_t ws_size,
                              hipStream_t stream) {
    const float* tokens = (const float*)d_in[0];
    const float* fh_w1  = (const float*)d_in[1];
    const float* fh_b1  = (const float*)d_in[2];
    const float* fh_w2  = (const float*)d_in[3];
    const float* fh_b2  = (const float*)d_in[4];
    const float* wp_w1  = (const float*)d_in[5];
    const float* wp_b1  = (const float*)d_in[6];
    const float* wp_w2  = (const float*)d_in[7];
    const float* wp_b2  = (const float*)d_in[8];
    float* out = (float*)d_out;

    char* ws = (char*)d_ws;
    float*           h1f  = (float*)(ws + B_H1F);
    float*           fpad = (float*)(ws + B_FPAD);
    __hip_bfloat16*  h1wb = (__hip_bfloat16*)(ws + B_H1WB);
    __hip_bfloat16*  tokb = (__hip_bfloat16*)(ws + B_TOK);
    __hip_bfloat16*  wtb  = (__hip_bfloat16*)(ws + B_WTB);
    __hip_bfloat16*  wt2b = (__hip_bfloat16*)(ws + B_WT2B);
    __hip_bfloat16*  wraw = (__hip_bfloat16*)(ws + B_WRAW);   // aliases tokb+wtb
    const char*      zp   = (const char*)(ws + B_ZERO);

    // zero padded fp32 activation buffers (h1f+fpad) + zero page
    hipMemsetAsync(ws + B_H1F, 0, B_H1WB - B_H1F, stream);
    hipMemsetAsync(ws + B_ZERO, 0, 2048, stream);

    // packing
    cast_tok<<<2048, 256, 0, stream>>>(tokens, tokb, BB * NPOS * CIN / 4);
    build_wtb<<<(NCO * CIN + 255) / 256, 256, 0, stream>>>(fh_w1, wp_w1, wtb);
    cast_wt2b<<<(KOUTP * HID + 255) / 256, 256, 0, stream>>>(wp_w2, wt2b);

    // big conv pair as one MFMA implicit GEMM (BM=64, grid 1408)
    conv1_mfma<<<1408, 256, 0, stream>>>(tokb, wtb, fh_b1, wp_b1, zp, h1f, h1wb);

    // flow conv (256->3), scaled by P, into padded fpad
    conv3_small<<<(BB * NPOS + 31) / 32, 256, 0, stream>>>(h1f, fh_w2, fh_b2, fpad);

    // wraw GEMM + tail, two batch-halves (wraw reuses tokb/wtb space, now dead)
    for (int half = 0; half < 2; ++half) {
        wraw_gemm<<<1232, 256, 0, stream>>>(
            h1wb + (size_t)half * 8 * NPOS * HID, wt2b, wp_b2, wraw);
        up_tail<<<dim3(172, 8), 256, 0, stream>>>(wraw, fpad, out, half);
    }
}